// Round 9
// baseline (259.096 us; speedup 1.0000x reference)
//
#include <hip/hip_runtime.h>
#include <hip/hip_bf16.h>

// Problem constants (match reference)
#define HH 1024
#define WW 1024
#define NN (HH * WW)
#define KK 15
#define GAMMA_F 0.5f

// Block = 4 rows x 256 cols (256 threads, 4 adjacent cols per thread).
// Image window rows y0-4..y0+7, cols c0-4..c0+259 -> 12 x 264 tile, 38 KB.
#define TR 12
#define TW 264

// Async global->LDS DMA, 16B/lane, exec-masked; HW writes dest + lane*16.
__device__ __forceinline__ void cp16(const float* g, float* l) {
    __builtin_amdgcn_global_load_lds(
        (const __attribute__((address_space(1))) void*)g,
        (__attribute__((address_space(3))) void*)l, 16, 0, 0);
}

__global__ __launch_bounds__(256) void ppr_kernel(
    const float* __restrict__ s1,      // (N,)
    const float* __restrict__ s2,      // (2, N)
    const float* __restrict__ w,       // (K, N)
    const int* __restrict__ nb,        // (K, N)
    float* __restrict__ out)           // scalar
{
    __shared__ __align__(16) float t1 [TR * TW];
    __shared__ __align__(16) float t2a[TR * TW];
    __shared__ __align__(16) float t2b[TR * TW];
    __shared__ float smem[4];

    const int tid  = threadIdx.x;
    const int wv   = tid >> 6;                 // 0..3 -> pixel row within tile
    const int lane = tid & 63;
    const int ty   = blockIdx.x >> 2;          // row band 0..255
    const int tx   = blockIdx.x & 3;           // col tile 0..3
    const int y0   = ty << 2;
    const int c0   = tx << 8;
    const int yc   = y0 + wv;
    const int xc0  = c0 + (lane << 2);         // this thread's 4 cols
    const int n    = (yc << 10) + xc0;         // 16B aligned
    const int t4   = n >> 2;

    // ---- Phase 1: DMA the 12x264 window (3 arrays x 12 rows, 2 ops each =
    // 72 ops, 18/wave). Edge tiles shift the source start instead of
    // clamping; skipped LDS cells are clamped-away coords, never read.
    const int mainXs  = (tx == 0) ? 0   : c0 - 4;
    const int mainDof = (tx == 0) ? 4   : 0;
    const int tailXs  = (tx == 0) ? 256 : c0 + 252;
    const int tailDof = (tx == 0) ? 260 : 256;
    const int tailLn  = (tx == 0 || tx == 3) ? 1 : 2;

#pragma unroll
    for (int it = 0; it < 9; ++it) {
        const int t   = wv * 9 + it;           // 0..35, wave-uniform
        const int arr = t / 12;                // 0:s1 1:s2a 2:s2b
        const int rr  = t - arr * 12;          // tile row 0..11
        int gy = y0 - 4 + rr;
        gy = gy < 0 ? 0 : (gy > HH - 1 ? HH - 1 : gy);
        const float* src =
            (arr == 0 ? s1 : (arr == 1 ? s2 : s2 + NN)) + (size_t)gy * WW;
        float* dst = (arr == 0 ? t1 : (arr == 1 ? t2a : t2b)) + rr * TW;
        cp16(src + mainXs + lane * 4, dst + mainDof);          // 64 lanes
        if (lane < tailLn) cp16(src + tailXs + lane * 4, dst + tailDof);
    }

    // ---- Phase 2: chunk-A streams (k=0..7) into VGPRs, dwordx4.
    int4   j4[KK];
    float4 w4[KK];
#pragma unroll
    for (int k = 0; k < 8; ++k) j4[k] = ((const int4*)(nb + (size_t)k * NN))[t4];
#pragma unroll
    for (int k = 0; k < 8; ++k) w4[k] = ((const float4*)(w + (size_t)k * NN))[t4];

    __builtin_amdgcn_sched_barrier(0);  // keep all loads issued up-front
    __syncthreads();                    // vmcnt(0): DMA + chunk A complete

    // ---- Phase 3: chunk-B streams (k=8..14), in flight under chunk-A math.
#pragma unroll
    for (int k = 8; k < KK; ++k) j4[k] = ((const int4*)(nb + (size_t)k * NN))[t4];
#pragma unroll
    for (int k = 8; k < KK; ++k) w4[k] = ((const float4*)(w + (size_t)k * NN))[t4];
    __builtin_amdgcn_sched_barrier(0);

    // Own-pixel values: float4 LDS reads from the tile center row.
    const int own = (wv + 4) * TW + (lane << 2) + 4;
    const float4 s14 = *(const float4*)(t1  + own);
    const float4 sa4 = *(const float4*)(t2a + own);
    const float4 sb4 = *(const float4*)(t2b + own);
    const float s1n[4] = { s14.x, s14.y, s14.z, s14.w };
    const float sa [4] = { sa4.x, sa4.y, sa4.z, sa4.w };
    const float sb [4] = { sb4.x, sb4.y, sb4.z, sb4.w };

    // Refactor: plane = sa*(xc-xn) + sb*(yc-yn) = (sa*xc + sb*yc) - P,
    // a1 = (s1n - g1 - plane)*wk = (D + (P - g1))*wk,  D = s1n - sa*xc - sb*yc.
    const float ycf = (float)yc;
    float D[4];
#pragma unroll
    for (int i = 0; i < 4; ++i)
        D[i] = s1n[i] - fmaf(sa[i], (float)(xc0 + i), sb[i] * ycf);

    // LDS index for neighbor (yn,xn): yn*TW + xn + cbase
    const int cbase = (4 - y0) * TW + 4 - c0;

    float acc1[4] = {0.f, 0.f, 0.f, 0.f};
    float acc2[4] = {0.f, 0.f, 0.f, 0.f};
#pragma unroll
    for (int k = 0; k < KK; ++k) {
        const int   jjs[4] = { j4[k].x, j4[k].y, j4[k].z, j4[k].w };
        const float wks[4] = { w4[k].x, w4[k].y, w4[k].z, w4[k].w };
#pragma unroll
        for (int i = 0; i < 4; ++i) {
            const unsigned jj = (unsigned)jjs[i];
            const int yn = jj >> 10;
            const int xn = jj & (WW - 1);
            const int off = yn * TW + xn + cbase;
            const float g1  = t1 [off];
            const float g2a = t2a[off];
            const float g2b = t2b[off];

            const float P  = fmaf(sa[i], (float)xn, sb[i] * (float)yn);
            const float a1 = (D[i] + (P - g1)) * wks[i];
            acc1[i] = fmaf(a1, a1, acc1[i]);

            const float e0 = sa[i] - g2a;
            const float e1 = sb[i] - g2b;
            acc2[i] = fmaf(sqrtf(fmaf(e0, e0, e1 * e1)), wks[i], acc2[i]);
        }
    }

    float local = 0.0f;
#pragma unroll
    for (int i = 0; i < 4; ++i)
        local += sqrtf(acc1[i]) + GAMMA_F * acc2[i];

    // ---- Wave (64-lane) then block reduction, one atomic per block.
#pragma unroll
    for (int off2 = 32; off2 > 0; off2 >>= 1)
        local += __shfl_down(local, off2, 64);

    if (lane == 0) smem[wv] = local;
    __syncthreads();

    if (tid == 0) {
        const float s = smem[0] + smem[1] + smem[2] + smem[3];
        atomicAdd(out, s * (1.0f / (float)NN));  // MULTIPLIER == 1.0
    }
}

extern "C" void kernel_launch(void* const* d_in, const int* in_sizes, int n_in,
                              void* d_out, int out_size, void* d_ws, size_t ws_size,
                              hipStream_t stream) {
    const float* s1   = (const float*)d_in[0];  // sig1 (1,1,H,W)
    const float* s2   = (const float*)d_in[1];  // sig2 (1,2,H,W)
    const float* w    = (const float*)d_in[2];  // weights (K,N)
    // d_in[3] (dist) unused: derived exactly from neighbours.
    const int*   nb   = (const int*)d_in[4];    // neighbours (K,N)
    float* out = (float*)d_out;

    // d_out is re-poisoned to 0xAA before every timed launch; zero it first.
    hipMemsetAsync(out, 0, sizeof(float) * (size_t)out_size, stream);

    const int block = 256;
    const int grid  = NN / (block * 4);   // 1024 blocks, exact
    ppr_kernel<<<grid, block, 0, stream>>>(s1, s2, w, nb, out);
}

// Round 10
// 254.572 us; speedup vs baseline: 1.0178x; 1.0178x over previous
//
#include <hip/hip_runtime.h>
#include <hip/hip_bf16.h>

// Problem constants (match reference)
#define HH 1024
#define WW 1024
#define NN (HH * WW)
#define KK 15
#define GAMMA_F 0.5f

// Tile = 4 rows x 64 cols (1 px/thread). Window 12 x 72 per tile (10.4 KB x3).
// Each block pipelines TPB consecutive tiles with double-buffered LDS windows
// and double register sets for the nb/w streams: issue t+1, compute t.
#define TR 12
#define TW 72
#define TPB 4

// Async global->LDS DMA, 16B/lane, exec-masked; HW writes dest + lane*16.
__device__ __forceinline__ void cp16(const float* g, float* l) {
    __builtin_amdgcn_global_load_lds(
        (const __attribute__((address_space(1))) void*)g,
        (__attribute__((address_space(3))) void*)l, 16, 0, 0);
}

__global__ __launch_bounds__(256) void ppr_kernel(
    const float* __restrict__ s1,      // (N,)
    const float* __restrict__ s2,      // (2, N)
    const float* __restrict__ w,       // (K, N)
    const int* __restrict__ nb,        // (K, N)
    float* __restrict__ out)           // scalar
{
    __shared__ __align__(16) float t1 [2][TR * TW];
    __shared__ __align__(16) float t2a[2][TR * TW];
    __shared__ __align__(16) float t2b[2][TR * TW];
    __shared__ float smem[4];

    const int tid  = threadIdx.x;
    const int wv   = tid >> 6;
    const int lane = tid & 63;
    const int tile0 = blockIdx.x * TPB;   // 4 consecutive col-tiles, same band

    int   jj [2][KK];
    float wk2[2][KK];
    float local = 0.0f;

    // Issue all memory for `tile` into buffer/register-set `buf`.
    auto issue_tile = [&](int tile, int buf) {
        const int ty = tile >> 4, tx = tile & 15;
        const int y0 = ty << 2,  c0 = tx << 6;
        const int n  = ((y0 + wv) << 10) + c0 + lane;

        // nb/w streams into VGPRs (pass-through data, only thread n uses them).
#pragma unroll
        for (int k = 0; k < KK; ++k) jj[buf][k]  = nb[(size_t)k * NN + n];
#pragma unroll
        for (int k = 0; k < KK; ++k) wk2[buf][k] = w[(size_t)k * NN + n];

        // 12x72 window DMA: 3 arrays x 12 rows = 36 ops, 9 per wave.
        // Edge tiles shift the source start; skipped cells are clamped-away
        // coords the reference never reads.
        int xs = c0 - 4, dof = 0, nl = 18;
        if (tx == 0)       { xs = 0; dof = 4; nl = 17; }
        else if (tx == 15) { nl = 17; }

#pragma unroll
        for (int it = 0; it < 9; ++it) {
            const int t   = wv * 9 + it;       // 0..35, wave-uniform
            const int arr = t / 12;            // 0:s1 1:s2a 2:s2b
            const int rr  = t - arr * 12;      // tile row 0..11
            int gy = y0 - 4 + rr;
            gy = gy < 0 ? 0 : (gy > HH - 1 ? HH - 1 : gy);
            const float* src =
                (arr == 0 ? s1 : (arr == 1 ? s2 : s2 + NN)) + (size_t)gy * WW + xs;
            float* dst =
                (arr == 0 ? t1[buf] : (arr == 1 ? t2a[buf] : t2b[buf]))
                + rr * TW + dof;
            if (lane < nl) cp16(src + lane * 4, dst);
        }
    };

    // Consume `tile` from buffer/register-set `buf`.
    auto compute_tile = [&](int tile, int buf) {
        const int ty = tile >> 4, tx = tile & 15;
        const int y0 = ty << 2,  c0 = tx << 6;
        const int yc = y0 + wv,  xc = c0 + lane;

        const int own = (wv + 4) * TW + lane + 4;
        const float s1n = t1[buf][own];
        const float sa  = t2a[buf][own];
        const float sb  = t2b[buf][own];
        // plane refactor (validated R9): a1 = (D + (P - g1)) * wk,
        // D = s1n - sa*xc - sb*yc,  P = sa*xn + sb*yn.
        const float D = s1n - fmaf(sa, (float)xc, sb * (float)yc);
        const int cbase = (4 - y0) * TW + 4 - c0;

        float acc1 = 0.0f, acc2 = 0.0f;
#pragma unroll
        for (int k = 0; k < KK; ++k) {
            const unsigned j = (unsigned)jj[buf][k];
            const float  wkk = wk2[buf][k];
            const int yn = j >> 10;
            const int xn = j & (WW - 1);
            const int off = yn * TW + xn + cbase;
            const float g1  = t1 [buf][off];
            const float g2a = t2a[buf][off];
            const float g2b = t2b[buf][off];

            const float P  = fmaf(sa, (float)xn, sb * (float)yn);
            const float a1 = (D + (P - g1)) * wkk;
            acc1 = fmaf(a1, a1, acc1);

            const float e0 = sa - g2a;
            const float e1 = sb - g2b;
            acc2 = fmaf(sqrtf(fmaf(e0, e0, e1 * e1)), wkk, acc2);
        }
        local += sqrtf(acc1) + GAMMA_F * acc2;
    };

    // ---- Pipeline: barrier lands tile t; issue t+1; compute t.
    issue_tile(tile0, 0);
#pragma unroll
    for (int t = 0; t < TPB; ++t) {
        __syncthreads();                      // vmcnt(0): tile t's DMA+loads done
        if (t + 1 < TPB) issue_tile(tile0 + t + 1, (t + 1) & 1);
        __builtin_amdgcn_sched_barrier(0);    // keep t+1 issue above compute t
        compute_tile(tile0 + t, t & 1);
    }

    // ---- Wave (64-lane) then block reduction, one atomic per block.
#pragma unroll
    for (int off2 = 32; off2 > 0; off2 >>= 1)
        local += __shfl_down(local, off2, 64);

    if (lane == 0) smem[wv] = local;
    __syncthreads();

    if (tid == 0) {
        const float s = smem[0] + smem[1] + smem[2] + smem[3];
        atomicAdd(out, s * (1.0f / (float)NN));  // MULTIPLIER == 1.0
    }
}

extern "C" void kernel_launch(void* const* d_in, const int* in_sizes, int n_in,
                              void* d_out, int out_size, void* d_ws, size_t ws_size,
                              hipStream_t stream) {
    const float* s1   = (const float*)d_in[0];  // sig1 (1,1,H,W)
    const float* s2   = (const float*)d_in[1];  // sig2 (1,2,H,W)
    const float* w    = (const float*)d_in[2];  // weights (K,N)
    // d_in[3] (dist) unused: derived exactly from neighbours.
    const int*   nb   = (const int*)d_in[4];    // neighbours (K,N)
    float* out = (float*)d_out;

    // d_out is re-poisoned to 0xAA before every timed launch; zero it first.
    hipMemsetAsync(out, 0, sizeof(float) * (size_t)out_size, stream);

    const int block = 256;
    const int grid  = NN / (block * TPB);   // 1024 blocks, 4 tiles each
    ppr_kernel<<<grid, block, 0, stream>>>(s1, s2, w, nb, out);
}

// Round 11
// 244.176 us; speedup vs baseline: 1.0611x; 1.0426x over previous
//
#include <hip/hip_runtime.h>
#include <hip/hip_bf16.h>

// Problem constants (match reference)
#define HH 1024
#define WW 1024
#define NN (HH * WW)
#define KK 15
#define GAMMA_F 0.5f

// Block = 4 rows x 128 cols (256 threads, 2 adjacent cols per thread).
// Image window rows y0-4..y0+7, cols c0-4..c0+131 -> 12 x 136 tile, 19.6 KB.
#define TR 12
#define TW 136
#define NBLK (NN / 512)   // 2048 blocks

// Async global->LDS DMA, 16B/lane, exec-masked; HW writes dest + lane*16.
__device__ __forceinline__ void cp16(const float* g, float* l) {
    __builtin_amdgcn_global_load_lds(
        (const __attribute__((address_space(1))) void*)g,
        (__attribute__((address_space(3))) void*)l, 16, 0, 0);
}

__global__ __launch_bounds__(256) void ppr_kernel(
    const float* __restrict__ s1,      // (N,)
    const float* __restrict__ s2,      // (2, N)
    const float* __restrict__ w,       // (K, N)
    const int* __restrict__ nb,        // (K, N)
    float* __restrict__ partial)       // (NBLK,)
{
    __shared__ __align__(16) float t1 [TR * TW];
    __shared__ __align__(16) float t2a[TR * TW];
    __shared__ __align__(16) float t2b[TR * TW];
    __shared__ float smem[4];

    const int tid  = threadIdx.x;
    const int wv   = tid >> 6;                 // 0..3 -> pixel row within tile
    const int lane = tid & 63;
    const int ty   = blockIdx.x >> 3;          // row band 0..255
    const int tx   = blockIdx.x & 7;           // col tile 0..7
    const int y0   = ty << 2;
    const int c0   = tx << 7;
    const int yc   = y0 + wv;
    const int xc0  = c0 + (lane << 1);         // this thread's 2 cols
    const int n    = (yc << 10) + xc0;         // even -> 8B aligned

    // ---- Chunk A streams (k=0..7) into VGPRs, dwordx2, pinned up-front.
    int2   jA[8];
    float2 wA[8];
#pragma unroll
    for (int k = 0; k < 8; ++k) jA[k] = *(const int2*)(nb + (size_t)k * NN + n);
#pragma unroll
    for (int k = 0; k < 8; ++k) wA[k] = *(const float2*)(w + (size_t)k * NN + n);

    // ---- DMA the 12x136 window: 3 arrays x 3 rows per wave, no divisions.
    // Edge tiles shift the source start; skipped LDS cells are clamped-away
    // coords the reference never reads.
    int xs = c0 - 4, dof = 0, nl = 34;
    if (tx == 0)      { xs = 0; dof = 4; nl = 33; }
    else if (tx == 7) { nl = 33; }
    const bool on = (lane < nl);

    const float* const srcs[3] = { s1, s2, s2 + NN };
    float* const       dsts[3] = { t1, t2a, t2b };
#pragma unroll
    for (int arr = 0; arr < 3; ++arr) {
#pragma unroll
        for (int r3 = 0; r3 < 3; ++r3) {
            const int rr = wv + (r3 << 2);     // rows wv, wv+4, wv+8
            int gy = y0 - 4 + rr;
            gy = gy < 0 ? 0 : (gy > HH - 1 ? HH - 1 : gy);
            if (on) cp16(srcs[arr] + (size_t)gy * WW + xs + lane * 4,
                         dsts[arr] + rr * TW + dof);
        }
    }

    __builtin_amdgcn_sched_barrier(0);  // keep chunk A + DMA issued up-front
    __syncthreads();                    // vmcnt(0): DMA + chunk A complete

    // ---- Chunk B streams (k=8..14): latency hides under chunk-A compute.
    int2   jB[7];
    float2 wB[7];
#pragma unroll
    for (int k = 0; k < 7; ++k)
        jB[k] = *(const int2*)(nb + (size_t)(k + 8) * NN + n);
#pragma unroll
    for (int k = 0; k < 7; ++k)
        wB[k] = *(const float2*)(w + (size_t)(k + 8) * NN + n);
    __builtin_amdgcn_sched_barrier(0);  // keep B issue above A compute

    // Own-pixel values from the tile center row.
    const int own0 = (wv + 4) * TW + (lane << 1) + 4;
    const float s1n_0 = t1 [own0], s1n_1 = t1 [own0 + 1];
    const float sa_0  = t2a[own0], sa_1  = t2a[own0 + 1];
    const float sb_0  = t2b[own0], sb_1  = t2b[own0 + 1];

    // plane refactor: a1 = (D + (P - g1))*wk, D = s1n - sa*xc - sb*yc,
    // P = sa*xn + sb*yn  (exact same fp32 ops count, fewer int->fp converts).
    const float ycf = (float)yc;
    const float D0 = s1n_0 - fmaf(sa_0, (float)xc0,       sb_0 * ycf);
    const float D1 = s1n_1 - fmaf(sa_1, (float)(xc0 + 1), sb_1 * ycf);

    // LDS index for neighbor (yn,xn): yn*TW + xn + cbase
    const int cbase = (4 - y0) * TW + 4 - c0;

    float acc1_0 = 0.f, acc2_0 = 0.f, acc1_1 = 0.f, acc2_1 = 0.f;

    auto body = [&](int2 j2, float2 w2) {
        {   // pixel 0
            const unsigned jj = (unsigned)j2.x;
            const int yn = jj >> 10;
            const int xn = jj & (WW - 1);
            const int off = yn * TW + xn + cbase;
            const float g1  = t1 [off];
            const float g2a = t2a[off];
            const float g2b = t2b[off];
            const float P  = fmaf(sa_0, (float)xn, sb_0 * (float)yn);
            const float a1 = (D0 + (P - g1)) * w2.x;
            acc1_0 = fmaf(a1, a1, acc1_0);
            const float e0 = sa_0 - g2a;
            const float e1 = sb_0 - g2b;
            acc2_0 = fmaf(sqrtf(fmaf(e0, e0, e1 * e1)), w2.x, acc2_0);
        }
        {   // pixel 1
            const unsigned jj = (unsigned)j2.y;
            const int yn = jj >> 10;
            const int xn = jj & (WW - 1);
            const int off = yn * TW + xn + cbase;
            const float g1  = t1 [off];
            const float g2a = t2a[off];
            const float g2b = t2b[off];
            const float P  = fmaf(sa_1, (float)xn, sb_1 * (float)yn);
            const float a1 = (D1 + (P - g1)) * w2.y;
            acc1_1 = fmaf(a1, a1, acc1_1);
            const float e0 = sa_1 - g2a;
            const float e1 = sb_1 - g2b;
            acc2_1 = fmaf(sqrtf(fmaf(e0, e0, e1 * e1)), w2.y, acc2_1);
        }
    };

#pragma unroll
    for (int k = 0; k < 8; ++k) body(jA[k], wA[k]);   // chunk A
#pragma unroll
    for (int k = 0; k < 7; ++k) body(jB[k], wB[k]);   // chunk B (vmcnt waits)

    float local = sqrtf(acc1_0) + sqrtf(acc1_1) + GAMMA_F * (acc2_0 + acc2_1);

    // ---- Wave (64-lane) then block reduction; race-free partial store.
#pragma unroll
    for (int off2 = 32; off2 > 0; off2 >>= 1)
        local += __shfl_down(local, off2, 64);

    if (lane == 0) smem[wv] = local;
    __syncthreads();

    if (tid == 0)
        partial[blockIdx.x] = smem[0] + smem[1] + smem[2] + smem[3];
}

// Reduce 2048 partials -> out[0]. Single block, no atomics, no memset needed.
__global__ __launch_bounds__(256) void ppr_reduce(
    const float* __restrict__ partial, float* __restrict__ out)
{
    const int tid = threadIdx.x;
    const float4 a = ((const float4*)partial)[tid];
    const float4 b = ((const float4*)partial)[tid + 256];
    float v = (a.x + a.y) + (a.z + a.w) + (b.x + b.y) + (b.z + b.w);

#pragma unroll
    for (int off = 32; off > 0; off >>= 1)
        v += __shfl_down(v, off, 64);

    __shared__ float sm[4];
    if ((tid & 63) == 0) sm[tid >> 6] = v;
    __syncthreads();
    if (tid == 0)
        out[0] = (sm[0] + sm[1] + sm[2] + sm[3]) * (1.0f / (float)NN);
}

extern "C" void kernel_launch(void* const* d_in, const int* in_sizes, int n_in,
                              void* d_out, int out_size, void* d_ws, size_t ws_size,
                              hipStream_t stream) {
    const float* s1   = (const float*)d_in[0];  // sig1 (1,1,H,W)
    const float* s2   = (const float*)d_in[1];  // sig2 (1,2,H,W)
    const float* w    = (const float*)d_in[2];  // weights (K,N)
    // d_in[3] (dist) unused: derived exactly from neighbours.
    const int*   nb   = (const int*)d_in[4];    // neighbours (K,N)
    float* out     = (float*)d_out;
    float* partial = (float*)d_ws;              // 2048 floats of scratch

    ppr_kernel<<<NBLK, 256, 0, stream>>>(s1, s2, w, nb, partial);
    ppr_reduce<<<1, 256, 0, stream>>>(partial, out);
}